// Round 14
// baseline (64.981 us; speedup 1.0000x reference)
//
#include <hip/hip_runtime.h>

// PNN / RBF classifier, MI355X. Round 14: ZERO-SYNC all-register fp4 GEMM.
// Cross-round accounting: MFMA-busy always == dtype floor (r2 13.9us bf16,
// r8 6.2 fp8, r10 3.1 fp4) while duration is pinned at ~36-58us across ALL
// structures -> the wall is a delivery/sync term. The one never-removed
// element: dependent gll->vmcnt->barrier chains. This kernel removes sync
// entirely: A panel AND B tiles in registers via plain coalesced loads
// (compiler-managed waitcnts), zero barriers after prologue, zero manual
// vmcnt, branchless wave-skip epilogue. Persistent 256 blocks, 4 tiles each.
// dist2(q,t) = xx[q]+tt[t]-2*dot. exp(-dist2/8) underflows fp32-normal unless
// dist2 < 698.69 (FTZ matches XLA ref; verified r1-r13, absmax=0). fp4 GEMM is
// only a SCREEN (threshold 750): flagged pairs recomputed exactly in fp32.
// Nothing enters classacc unconfirmed -> correctness unconditional.
//
// fp4 packed layout (r10/r12): chunk(rt,kt) = 1024 B at (rt*8+kt)*1024; lane
// slot l = (row&31)+32*((k>>5)&1) holds its 32 k-elems (16 B) at l*16. MFMA
// lane reads exactly [lane*16, +16) of a chunk -> one dwordx4 per operand.

#define NQ 4096
#define NT 8192
#define DD 512
#define NC 16
#define LN_FLT_MIN -87.336544750402f
#define SCREEN_T 750.0f

typedef __attribute__((ext_vector_type(4))) int   v4i;
typedef __attribute__((ext_vector_type(8))) int   v8i;
typedef __attribute__((ext_vector_type(16))) float f32x16;

static __device__ __forceinline__ unsigned f2fp4(float x) {
  // e2m1 RTNE via thresholds; levels 0,.5,1,1.5,2,3,4,6 (sat at 6)
  const float a = __builtin_fabsf(x);
  unsigned i = (unsigned)(a >= 0.25f) + (a >= 0.75f) + (a >= 1.25f)
             + (a >= 1.75f) + (a >= 2.5f) + (a >= 3.5f) + (a >= 5.0f);
  return i | (x < 0.0f ? 8u : 0u);
}

__global__ __launch_bounds__(256) void prep_k(const float* __restrict__ X,
                                              const float* __restrict__ XT,
                                              unsigned char* __restrict__ fXp,
                                              unsigned char* __restrict__ fTp,
                                              float* __restrict__ xx,
                                              float* __restrict__ tt,
                                              float* __restrict__ classacc) {
  const int lane = threadIdx.x & 63;
  const int row  = blockIdx.x * 4 + (threadIdx.x >> 6);
  const float* src; unsigned char* dst; float* nrm; int r;
  if (row < NT) { r = row; src = XT + (size_t)r * DD; dst = fTp; nrm = tt + r; }
  else { r = row - NT; src = X + (size_t)r * DD; dst = fXp; nrm = xx + r; }
  const float4* s4 = (const float4*)src;
  const float4 a = s4[lane * 2], b = s4[lane * 2 + 1];   // k = lane*8 .. +7
  const unsigned word =  f2fp4(a.x)        | (f2fp4(a.y) << 4)
                      | (f2fp4(a.z) << 8)  | (f2fp4(a.w) << 12)
                      | (f2fp4(b.x) << 16) | (f2fp4(b.y) << 20)
                      | (f2fp4(b.z) << 24) | (f2fp4(b.w) << 28);
  const int l = (r & 31) + 32 * ((lane >> 2) & 1);
  const size_t dest = ((size_t)(r >> 5) * 8 + (lane >> 3)) * 1024
                    + l * 16 + (lane & 3) * 4;
  *(unsigned*)(dst + dest) = word;
  float acc = a.x*a.x + a.y*a.y + a.z*a.z + a.w*a.w
            + b.x*b.x + b.y*b.y + b.z*b.z + b.w*b.w;
  #pragma unroll
  for (int off = 32; off; off >>= 1) acc += __shfl_down(acc, off, 64);
  if (lane == 0) *nrm = acc;
  if (blockIdx.x < 64) {
    float4 z = {0.f, 0.f, 0.f, 0.f};
    ((float4*)classacc)[blockIdx.x * 256 + threadIdx.x] = z;
  }
}

#define MFMA4(A, B, C) __builtin_amdgcn_mfma_scale_f32_32x32x64_f8f6f4( \
    (A), (B), (C), 4, 4, 0, 127, 0, 127)   // fmt 4 = FP4 e2m1; 127 = x1.0

static __device__ __forceinline__ v8i pk8(v4i lo) {
  return __builtin_shufflevector(lo, lo, 0, 1, 2, 3, -1, -1, -1, -1); // fp4 uses v[0:3]
}

__global__ __launch_bounds__(512) void pnn_mfma(const unsigned char* __restrict__ fXp,
                                                const unsigned char* __restrict__ fTp,
                                                const float* __restrict__ Xf,
                                                const float* __restrict__ Tf,
                                                const int* __restrict__ y,
                                                const float* __restrict__ sigp,
                                                const float* __restrict__ xx,
                                                const float* __restrict__ tt,
                                                float* __restrict__ classacc) {
  __shared__ float hxs[128];                  // screen thresholds (broadcast reads)
  const int tid  = threadIdx.x;
  const int w    = tid >> 6, lane = tid & 63;
  const int la   = lane & 31, lb = lane >> 5;
  const int wr   = w >> 2, wc = w & 3;        // 2M x 4N waves, 64x64 tiles

  // persistent: 256 blocks = 32 qt x 8 strips (strip = bid&7 ~ XCD).
  const int bid   = blockIdx.x;
  const int strip = bid & 7;
  const int qt    = bid >> 3;
  const int qbase = qt * 128;
  const int art   = (qbase >> 5) + wr * 2;    // wave's A row-tiles

  const float sg = sigp[0];
  const float inv2s2 = 1.0f / (2.0f * sg * sg);

  // ---- A panel -> registers (once per block): 16 v4i ----
  v4i av[2][8];
  #pragma unroll
  for (int mt = 0; mt < 2; ++mt)
    #pragma unroll
    for (int kt = 0; kt < 8; ++kt)
      av[mt][kt] = *(const v4i*)(fXp + ((size_t)(art + mt) * 8 + kt) * 1024 + lane * 16);

  if (tid < 128) hxs[tid] = (xx[qbase + tid] - SCREEN_T) * 0.5f;

  // ---- B tile 0 -> registers: 16 v4i (16 independent coalesced dwordx4) ----
  v4i bv[2][8];
  #pragma unroll
  for (int j = 0; j < 2; ++j)
    #pragma unroll
    for (int kt = 0; kt < 8; ++kt)
      bv[j][kt] = *(const v4i*)(fTp + ((size_t)(strip * 32 + wc * 2 + j) * 8 + kt) * 1024 + lane * 16);

  __syncthreads();                            // hxs visible (only barrier in kernel)

  #pragma clang loop unroll(disable)
  for (int t = 0; t < 4; ++t) {
    const int tbase = strip * 1024 + t * 256;
    const int wt = tbase + wc * 64;
    const float hn0 = tt[wt + la] * 0.5f;       // col-norm/2, nt=0
    const float hn1 = tt[wt + 32 + la] * 0.5f;  // nt=1

    f32x16 acc00 = (f32x16)(0.f), acc01 = (f32x16)(0.f);
    f32x16 acc10 = (f32x16)(0.f), acc11 = (f32x16)(0.f);

    #pragma unroll
    for (int kt = 0; kt < 8; ++kt) {          // pure reg compute
      const v8i a0 = pk8(av[0][kt]), a1 = pk8(av[1][kt]);
      const v8i b0 = pk8(bv[0][kt]), b1 = pk8(bv[1][kt]);
      acc00 = MFMA4(a0, b0, acc00);
      acc01 = MFMA4(a0, b1, acc01);
      acc10 = MFMA4(a1, b0, acc10);
      acc11 = MFMA4(a1, b1, acc11);
    }

    // issue next tile's B right after last use; epilogue hides the latency
    if (t < 3) {
      #pragma unroll
      for (int j = 0; j < 2; ++j)
        #pragma unroll
        for (int kt = 0; kt < 8; ++kt)
          bv[j][kt] = *(const v4i*)(fTp + ((size_t)(strip * 32 + (t + 1) * 8 + wc * 2 + j) * 8 + kt) * 1024 + lane * 16);
    }

    // ---- branchless-until-fired epilogue ----
    // screen: acc > hxs[ql] + tt[t]/2  (== dist2 < SCREEN_T). Per quadrant:
    // fmax-reduce(acc-hxs) then ONE expected-false branch (vs 16 exec-toggles).
    // C/D 32x32 map: col = la, row = (reg&3) + 8*(reg>>2) + 4*lb  [m74/m101]
#define EPQ(ACC, mt, HN, nt) { \
    float mx = -3.0e38f; \
    _Pragma("unroll") \
    for (int reg = 0; reg < 16; ++reg) { \
      const int ql = wr * 64 + (mt) * 32 + (reg & 3) + 8 * (reg >> 2) + 4 * lb; \
      mx = fmaxf(mx, (ACC)[reg] - hxs[ql]); \
    } \
    if (__builtin_expect(mx > (HN), 0)) { \
      _Pragma("unroll") \
      for (int reg = 0; reg < 16; ++reg) { \
        const int ql = wr * 64 + (mt) * 32 + (reg & 3) + 8 * (reg >> 2) + 4 * lb; \
        if ((ACC)[reg] - hxs[ql] > (HN)) { \
          const int q = qbase + ql; \
          const int tg = wt + (nt) * 32 + la; \
          const float4* xp = (const float4*)(Xf + (size_t)q * DD); \
          const float4* tp = (const float4*)(Tf + (size_t)tg * DD); \
          float s0 = 0.f, s1 = 0.f, s2 = 0.f, s3 = 0.f; \
          for (int d = 0; d < DD / 4; ++d) { \
            const float4 xv = xp[d], tv = tp[d]; \
            s0 = fmaf(xv.x, tv.x, s0); s1 = fmaf(xv.y, tv.y, s1); \
            s2 = fmaf(xv.z, tv.z, s2); s3 = fmaf(xv.w, tv.w, s3); \
          } \
          const float dot = (s0 + s1) + (s2 + s3); \
          const float dd2 = fmaxf(xx[q] + tt[tg] - 2.0f * dot, 0.f); \
          const float arg = -dd2 * inv2s2; \
          if (arg >= LN_FLT_MIN)          /* below: fp32 exp subnormal -> FTZ 0 */ \
            atomicAdd(&classacc[q * NC + y[tg]], expf(arg)); \
        } \
      } \
    } }

    EPQ(acc00, 0, hn0, 0)
    EPQ(acc01, 0, hn1, 1)
    EPQ(acc10, 1, hn0, 0)
    EPQ(acc11, 1, hn1, 1)
#undef EPQ
  }
}

__global__ __launch_bounds__(256) void argmax_k(const float* __restrict__ classacc,
                                                float* __restrict__ out) {
  const int q = blockIdx.x * 256 + threadIdx.x;
  float sc[NC];
  #pragma unroll
  for (int c4 = 0; c4 < 4; ++c4) {
    const float4 v = ((const float4*)(classacc + (size_t)q * NC))[c4];
    sc[c4*4+0] = v.x; sc[c4*4+1] = v.y; sc[c4*4+2] = v.z; sc[c4*4+3] = v.w;
  }
  float rowsum = 0.f;
  #pragma unroll
  for (int c = 0; c < NC; ++c) rowsum += sc[c];
  int best = 0; float bv = sc[0];
  #pragma unroll
  for (int c = 1; c < NC; ++c)
    if (sc[c] > bv) { bv = sc[c]; best = c; }   // strict > = first max (jnp.argmax)
  out[q] = (rowsum > 0.f) ? (float)best : 0.0f; // all-zero row -> NaN in ref -> 0
}

extern "C" void kernel_launch(void* const* d_in, const int* in_sizes, int n_in,
                              void* d_out, int out_size, void* d_ws, size_t ws_size,
                              hipStream_t stream) {
  const float* X  = (const float*)d_in[0];
  const float* XT = (const float*)d_in[1];
  const int*   y  = (const int*)d_in[2];
  const float* sg = (const float*)d_in[3];
  float* out = (float*)d_out;

  char* wsp = (char*)d_ws;
  unsigned char* fXp = (unsigned char*)wsp;                        // 1 MB fp4 packed
  unsigned char* fTp = fXp + (size_t)NQ * DD / 2;                  // 2 MB fp4 packed
  float* tt       = (float*)(wsp + 4u * 1024u * 1024u);            // NT f32
  float* xx       = tt + NT;                                       // NQ f32
  float* classacc = xx + NQ;                                       // 256 KB

  prep_k<<<(NQ + NT) / 4, 256, 0, stream>>>(X, XT, fXp, fTp, xx, tt, classacc);
  pnn_mfma<<<256, 512, 0, stream>>>(fXp, fTp, X, XT, y, sg, xx, tt, classacc);
  argmax_k<<<NQ / 256, 256, 0, stream>>>(classacc, out);
}

// Round 15
// 46.877 us; speedup vs baseline: 1.3862x; 1.3862x over previous
//
#include <hip/hip_runtime.h>

// PNN / RBF classifier, MI355X. Round 15: bf16 256x256 GEMM with a DEEP
// K-pipeline: BK=32, ring of 4 KT-slots per matrix (8 x 16 KB = 128 KiB LDS).
// KT k's stage is issued during KT k-3 -> ~3.6K cycles of latency tolerance
// (r4/r5's 2-buffer BK=64 schedules were only 1-KT-deep: every K-step paid a
// full L2/L3 round trip; that was the ~25us stall). One raw barrier + one
// counted vmcnt per KT. No forced launch bounds (r6/r11/r14 spill lesson).
// dist2(q,t) = xx[q]+tt[t]-2*dot. exp(-dist2/8) underflows fp32-normal unless
// dist2 < 698.69 (FTZ matches XLA ref; verified r1-r14, absmax=0). bf16 GEMM
// screens at 706 (r2/r4-verified); flagged pairs recomputed exactly in fp32.
// Nothing enters classacc unconfirmed -> correctness unconditional.
//
// vmcnt ledger (A/B unit = 2 loads each; prologue issues [xx],A0,B0,A1,B1,A2,B2;
// during KT k phase a: stage A(k+3), phase b: stage B(k+3), k<=12):
//   boundary k (before computing KT k): outstanding = units {A/B(k)..A/B(k+2)}
//   = 12 loads -> vmcnt(8) retires A(k),B(k). Tail: k=14 -> vmcnt(4),
//   k=15 -> vmcnt(0). The prologue xx load is older than A0 -> harmless.
// WAR: stage(k+3) targets slot (k+3)&3 = (k-1)&3, whose last reads were KT
// k-1 phase b, sequenced before boundary-k barrier. Ring depth 4 = safe.

#define NQ 4096
#define NT 8192
#define DD 512
#define NC 16
#define LN_FLT_MIN -87.336544750402f
#define SCREEN_T 706.0f

typedef __attribute__((ext_vector_type(8))) short bf16x8;
typedef __attribute__((ext_vector_type(4))) float f32x4;
typedef __attribute__((ext_vector_type(8))) unsigned short u16x8;

static __device__ __forceinline__ unsigned short f2bf(float f) {
  unsigned u = __float_as_uint(f);
  u = u + 0x7FFFu + ((u >> 16) & 1u);   // RTNE
  return (unsigned short)(u >> 16);
}

__global__ __launch_bounds__(256) void prep_k(const float* __restrict__ X,
                                              const float* __restrict__ XT,
                                              unsigned short* __restrict__ bX,
                                              unsigned short* __restrict__ bT,
                                              float* __restrict__ xx,
                                              float* __restrict__ tt,
                                              float* __restrict__ classacc) {
  const int lane = threadIdx.x & 63;
  const int row  = blockIdx.x * 4 + (threadIdx.x >> 6);
  const float* src; unsigned short* dst; float* nrm;
  if (row < NT) { src = XT + (size_t)row * DD; dst = bT + (size_t)row * DD; nrm = tt + row; }
  else { const int r = row - NT; src = X + (size_t)r * DD; dst = bX + (size_t)r * DD; nrm = xx + r; }
  const float4* s4 = (const float4*)src;
  const float4 a = s4[lane * 2], b = s4[lane * 2 + 1];
  u16x8 o;
  o[0] = f2bf(a.x); o[1] = f2bf(a.y); o[2] = f2bf(a.z); o[3] = f2bf(a.w);
  o[4] = f2bf(b.x); o[5] = f2bf(b.y); o[6] = f2bf(b.z); o[7] = f2bf(b.w);
  *((u16x8*)dst + lane) = o;
  float acc = a.x*a.x + a.y*a.y + a.z*a.z + a.w*a.w
            + b.x*b.x + b.y*b.y + b.z*b.z + b.w*b.w;
  #pragma unroll
  for (int off = 32; off; off >>= 1) acc += __shfl_down(acc, off, 64);
  if (lane == 0) *nrm = acc;
  if (blockIdx.x < 64) {
    float4 z = {0.f, 0.f, 0.f, 0.f};
    ((float4*)classacc)[blockIdx.x * 256 + threadIdx.x] = z;
  }
}

#define BAR() __builtin_amdgcn_s_barrier()
#define WAITV(N) asm volatile("s_waitcnt vmcnt(" #N ")" ::: "memory")

static __device__ __forceinline__ void gll(const void* src, char* dst) {
  __builtin_amdgcn_global_load_lds(
      (const __attribute__((address_space(1))) unsigned int*)src,
      (__attribute__((address_space(3))) unsigned int*)dst, 16, 0, 0);
}

// stage one KT unit: 256 rows x 64 B (16 KB), linear LDS dest, source col
// pre-XORed with the read-side swizzle: c ^= ((r>>1)&3)<<4  [rule #21].
static __device__ __forceinline__ void stage_unit(const unsigned short* __restrict__ src,
                                                  int rowbase, int kt,
                                                  char* dst, int tid) {
  #pragma unroll
  for (int j = 0; j < 2; ++j) {
    const int L = j * 8192 + tid * 16;
    const int r = L >> 6, c = L & 63;
    const int cs = c ^ (((r >> 1) & 3) << 4);
    gll((const char*)(src + (size_t)(rowbase + r) * DD) + kt * 64 + cs, dst + L);
  }
}

// fragment read: row-major [256][32] bf16 KT slot, swizzled; 16x16x32 A/B
// fragment = 16 B at (row, kbyte hi*16). Banks: 2-way max (free, m136).
static __device__ __forceinline__ bf16x8 frag(const char* slot, int row, int hi) {
  const int c = (hi * 16) ^ (((row >> 1) & 3) << 4);
  return *(const bf16x8*)(slot + row * 64 + c);
}

__global__ __launch_bounds__(512) void pnn_mfma(const unsigned short* __restrict__ bX,
                                                const unsigned short* __restrict__ bT,
                                                const float* __restrict__ Xf,
                                                const float* __restrict__ Tf,
                                                const int* __restrict__ y,
                                                const float* __restrict__ sigp,
                                                const float* __restrict__ xx,
                                                const float* __restrict__ tt,
                                                float* __restrict__ classacc) {
  extern __shared__ char lds[];   // A ring 4x16K | B ring 4x16K | hxs 1K
  float* const hxs = (float*)(lds + 131072);
  const int tid  = threadIdx.x;
  const int w    = tid >> 6, lane = tid & 63;
  const int lo   = lane & 15, hb = lane >> 4;
  const int wr   = w >> 2, wc = w & 3;        // 2M x 4N waves; wave tile 128x64

  // XCD map: 512 blocks; xcd = bid&7 owns tn {4x..4x+3} (B 1 MB L2-resident)
  const int bid = blockIdx.x;
  const int xcd = bid & 7, c = bid >> 3;      // c: 0..63
  const int tn  = xcd * 4 + (c & 3);
  const int qt  = c >> 2;
  const int qbase = qt * 256, tbase = tn * 256;

#define ASLOT(k) (lds + ((k) & 3) * 16384)
#define BSLOT(k) (lds + 65536 + ((k) & 3) * 16384)

  // ---- prologue: hxs source load FIRST (oldest in vm ledger), then 6 units
  float xv = 0.f;
  if (tid < 256) xv = xx[qbase + tid];        // 1 vmem (waves 0-3 only, oldest)
  stage_unit(bX, qbase, 0, ASLOT(0), tid);
  stage_unit(bT, tbase, 0, BSLOT(0), tid);
  stage_unit(bX, qbase, 1, ASLOT(1), tid);
  stage_unit(bT, tbase, 1, BSLOT(1), tid);
  stage_unit(bX, qbase, 2, ASLOT(2), tid);
  stage_unit(bT, tbase, 2, BSLOT(2), tid);
  if (tid < 256) hxs[tid] = (xv - SCREEN_T) * 0.5f;   // ds_write (lgkm, not vm)

  f32x4 acc[8][4];
  #pragma unroll
  for (int m = 0; m < 8; ++m)
    #pragma unroll
    for (int n = 0; n < 4; ++n) acc[m][n] = (f32x4)(0.f);

  #pragma unroll
  for (int k = 0; k < 16; ++k) {              // 16 KTs of 32; ring depth 4
    if (k <= 13) { WAITV(8); } else if (k == 14) { WAITV(4); } else { WAITV(0); }
    __builtin_amdgcn_sched_barrier(0);
    BAR();                                    // KT k resident; slot (k-1) free
    const char* As = ASLOT(k);
    const char* Bs = BSLOT(k);
    bf16x8 bfr[4], af[4];
    #pragma unroll
    for (int n = 0; n < 4; ++n) bfr[n] = frag(Bs, wc * 64 + n * 16 + lo, hb);
    #pragma unroll
    for (int m = 0; m < 4; ++m) af[m] = frag(As, wr * 128 + m * 16 + lo, hb);
    if (k <= 12) stage_unit(bX, qbase, k + 3, ASLOT(k + 3), tid);
    #pragma unroll
    for (int m = 0; m < 4; ++m)
      #pragma unroll
      for (int n = 0; n < 4; ++n)
        acc[m][n] = __builtin_amdgcn_mfma_f32_16x16x32_bf16(af[m], bfr[n], acc[m][n], 0, 0, 0);
    #pragma unroll
    for (int m = 0; m < 4; ++m) af[m] = frag(As, wr * 128 + (m + 4) * 16 + lo, hb);
    if (k <= 12) stage_unit(bT, tbase, k + 3, BSLOT(k + 3), tid);
    #pragma unroll
    for (int m = 0; m < 4; ++m)
      #pragma unroll
      for (int n = 0; n < 4; ++n)
        acc[m + 4][n] = __builtin_amdgcn_mfma_f32_16x16x32_bf16(af[m], bfr[n], acc[m + 4][n], 0, 0, 0);
  }

  // ---- epilogue: on-chip screen (acc > hxs[ql] + tt[t]/2 == dist2 < T);
  // rare path recomputes exact fp32 -> classacc atomic.
  // C/D 16x16 map: col = lane&15, row = (lane>>4)*4 + reg  [m89]
  const float sg = sigp[0];
  const float inv2s2 = 1.0f / (2.0f * sg * sg);
  float tnorm[4];
  #pragma unroll
  for (int n = 0; n < 4; ++n) tnorm[n] = tt[tbase + wc * 64 + n * 16 + lo] * 0.5f;

  #pragma unroll
  for (int m = 0; m < 8; ++m) {
    #pragma unroll
    for (int n = 0; n < 4; ++n) {
      #pragma unroll
      for (int r = 0; r < 4; ++r) {
        const int ql = wr * 128 + m * 16 + hb * 4 + r;
        if (__builtin_expect(acc[m][n][r] > hxs[ql] + tnorm[n], 0)) {
          const int q = qbase + ql;
          const int tg = tbase + wc * 64 + n * 16 + lo;
          const float4* xp = (const float4*)(Xf + (size_t)q * DD);
          const float4* tp = (const float4*)(Tf + (size_t)tg * DD);
          float s0 = 0.f, s1 = 0.f, s2 = 0.f, s3 = 0.f;
          for (int d = 0; d < DD / 4; ++d) {
            const float4 xw = xp[d], tw = tp[d];
            s0 = fmaf(xw.x, tw.x, s0); s1 = fmaf(xw.y, tw.y, s1);
            s2 = fmaf(xw.z, tw.z, s2); s3 = fmaf(xw.w, tw.w, s3);
          }
          const float dot = (s0 + s1) + (s2 + s3);
          const float dd2 = fmaxf(xx[q] + tt[tg] - 2.0f * dot, 0.f);
          const float arg = -dd2 * inv2s2;
          if (arg >= LN_FLT_MIN)              // below: fp32 exp subnormal -> FTZ 0
            atomicAdd(&classacc[q * NC + y[tg]], expf(arg));
        }
      }
    }
  }
}

__global__ __launch_bounds__(256) void argmax_k(const float* __restrict__ classacc,
                                                float* __restrict__ out) {
  const int q = blockIdx.x * 256 + threadIdx.x;
  float sc[NC];
  #pragma unroll
  for (int c4 = 0; c4 < 4; ++c4) {
    const float4 v = ((const float4*)(classacc + (size_t)q * NC))[c4];
    sc[c4*4+0] = v.x; sc[c4*4+1] = v.y; sc[c4*4+2] = v.z; sc[c4*4+3] = v.w;
  }
  float rowsum = 0.f;
  #pragma unroll
  for (int c = 0; c < NC; ++c) rowsum += sc[c];
  int best = 0; float bv = sc[0];
  #pragma unroll
  for (int c = 1; c < NC; ++c)
    if (sc[c] > bv) { bv = sc[c]; best = c; }   // strict > = first max (jnp.argmax)
  out[q] = (rowsum > 0.f) ? (float)best : 0.0f; // all-zero row -> NaN in ref -> 0
}

extern "C" void kernel_launch(void* const* d_in, const int* in_sizes, int n_in,
                              void* d_out, int out_size, void* d_ws, size_t ws_size,
                              hipStream_t stream) {
  const float* X  = (const float*)d_in[0];
  const float* XT = (const float*)d_in[1];
  const int*   y  = (const int*)d_in[2];
  const float* sg = (const float*)d_in[3];
  float* out = (float*)d_out;

  char* wsp = (char*)d_ws;
  unsigned short* bX = (unsigned short*)wsp;                       // 4 MB bf16
  unsigned short* bT = bX + (size_t)NQ * DD;                       // 8 MB bf16
  float* tt       = (float*)(wsp + 12u * 1024u * 1024u);           // NT f32
  float* xx       = tt + NT;                                       // NQ f32
  float* classacc = xx + NQ;                                       // 256 KB

  (void)hipFuncSetAttribute((const void*)pnn_mfma,
                            hipFuncAttributeMaxDynamicSharedMemorySize, 132096);

  prep_k<<<(NQ + NT) / 4, 256, 0, stream>>>(X, XT, bX, bT, xx, tt, classacc);
  pnn_mfma<<<512, 512, 132096, stream>>>(bX, bT, X, XT, y, sg, xx, tt, classacc);
  argmax_k<<<NQ / 256, 256, 0, stream>>>(classacc, out);
}